// Round 9
// baseline (3040.628 us; speedup 1.0000x reference)
//
#include <hip/hip_runtime.h>
#include <math.h>

#pragma clang fp contract(off)

namespace {

constexpr int kSteps = 32;

// ---- workspace layout (float slots) ----
constexpr size_t OFF_TEMPS = 0;        // 32 floats
constexpr size_t OFF_KEYS  = 64;       // 194 u32
constexpr size_t OFF_WP    = 512;      // 65536 (float4-packed W)
constexpr size_t OFF_WTP   = 66048;    // 65536 (float4-packed W^T)
constexpr size_t OFF_F2T   = 131584;   // 65536
constexpr size_t OFF_X1    = 197120;   // 524288
constexpr size_t OFF_BMOD  = 721408;   // 2097152
constexpr size_t OFF_CMOD  = 2818560;  // 2097152
constexpr size_t WS_FLOATS = 4915712;  // ~19.7 MB

// ================= threefry2x32 (JAX semantics) =================
__device__ __forceinline__ unsigned rotl32(unsigned v, int n) {
  return (v << n) | (v >> (32 - n));
}

__device__ __forceinline__ void tf_block(unsigned k0, unsigned k1,
                                         unsigned c0, unsigned c1,
                                         unsigned* o0, unsigned* o1) {
  unsigned k2 = k0 ^ k1 ^ 0x1BD11BDAu;
  unsigned x0 = c0 + k0;
  unsigned x1 = c1 + k1;
  x0 += x1; x1 = rotl32(x1, 13); x1 ^= x0;
  x0 += x1; x1 = rotl32(x1, 15); x1 ^= x0;
  x0 += x1; x1 = rotl32(x1, 26); x1 ^= x0;
  x0 += x1; x1 = rotl32(x1, 6);  x1 ^= x0;
  x0 += k1; x1 += k2 + 1u;
  x0 += x1; x1 = rotl32(x1, 17); x1 ^= x0;
  x0 += x1; x1 = rotl32(x1, 29); x1 ^= x0;
  x0 += x1; x1 = rotl32(x1, 16); x1 ^= x0;
  x0 += x1; x1 = rotl32(x1, 24); x1 ^= x0;
  x0 += k2; x1 += k0 + 2u;
  x0 += x1; x1 = rotl32(x1, 13); x1 ^= x0;
  x0 += x1; x1 = rotl32(x1, 15); x1 ^= x0;
  x0 += x1; x1 = rotl32(x1, 26); x1 ^= x0;
  x0 += x1; x1 = rotl32(x1, 6);  x1 ^= x0;
  x0 += k0; x1 += k1 + 3u;
  x0 += x1; x1 = rotl32(x1, 17); x1 ^= x0;
  x0 += x1; x1 = rotl32(x1, 29); x1 ^= x0;
  x0 += x1; x1 = rotl32(x1, 16); x1 ^= x0;
  x0 += x1; x1 = rotl32(x1, 24); x1 ^= x0;
  x0 += k1; x1 += k2 + 4u;
  x0 += x1; x1 = rotl32(x1, 13); x1 ^= x0;
  x0 += x1; x1 = rotl32(x1, 15); x1 ^= x0;
  x0 += x1; x1 = rotl32(x1, 26); x1 ^= x0;
  x0 += x1; x1 = rotl32(x1, 6);  x1 ^= x0;
  x0 += k2; x1 += k0 + 5u;
  *o0 = x0; *o1 = x1;
}

__device__ __forceinline__ float tf_uniform(unsigned k0, unsigned k1, unsigned idx) {
  unsigned o0, o1;
  tf_block(k0, k1, 0u, idx, &o0, &o1);
  unsigned bits = o0 ^ o1;
  float f = __uint_as_float((bits >> 9) | 0x3f800000u);
  return f - 1.0f;
}

// XLA EmitFastTanh (f32), plain mul/add.
__device__ __forceinline__ float xla_tanhf(float x) {
  if (fabsf(x) < 0.0004f) return x;
  float xc = fminf(fmaxf(x, -9.0f), 9.0f);
  float x2 = xc * xc;
  float num = -2.76076847742355e-16f;
  num = num * x2 + 2.00018790482477e-13f;
  num = num * x2 + -8.60467152213735e-11f;
  num = num * x2 + 5.12229709037114e-08f;
  num = num * x2 + 1.48572235717979e-05f;
  num = num * x2 + 6.37261928875436e-04f;
  num = num * x2 + 4.89352455891786e-03f;
  num = xc * num;
  float den = 1.19825839466702e-06f;
  den = den * x2 + 1.18534705686654e-04f;
  den = den * x2 + 2.26843463243900e-03f;
  den = den * x2 + 4.89352518554385e-03f;
  return num / den;
}

// XLA elemental kLogistic: 0.5 + 0.5 * tanh(0.5 * x)
__device__ __forceinline__ float xla_sigmoid(float x) {
  return 0.5f + 0.5f * xla_tanhf(0.5f * x);
}

// ================= setup kernels =================
__global__ __launch_bounds__(64) void kInitMeta(float* temps, unsigned* keys) {
  int t = threadIdx.x;
  if (t < 32) {
    float tf = (float)t;
    float arg = 0.1f * (tf - 16.0f);
    float e = (float)exp((double)arg);  // constant-folded by XLA w/ host expf
    float s = 1.0f / (1.0f + e);
    temps[t] = 1.0f + 4.0f * s;
  }
  if (t == 0) {
    unsigned cur0 = 0u, cur1 = 42u;  // jax.random.key(42)
    unsigned a0, a1, b0, b1;
    tf_block(cur0, cur1, 0u, 0u, &a0, &a1);  // carried key
    tf_block(cur0, cur1, 0u, 1u, &b0, &b1);  // init-v key
    keys[0] = b0; keys[1] = b1;
    cur0 = a0; cur1 = a1;
    for (int st = 0; st < kSteps; ++st) {
      unsigned n0, n1, kh0, kh1, ks0a, ks0b, kv0, kv1;
      tf_block(cur0, cur1, 0u, 0u, &n0, &n1);
      tf_block(cur0, cur1, 0u, 1u, &kh0, &kh1);
      tf_block(cur0, cur1, 0u, 2u, &ks0a, &ks0b);
      tf_block(cur0, cur1, 0u, 3u, &kv0, &kv1);
      keys[2 + st * 6 + 0] = kh0;  keys[2 + st * 6 + 1] = kh1;
      keys[2 + st * 6 + 2] = ks0a; keys[2 + st * 6 + 3] = ks0b;
      keys[2 + st * 6 + 4] = kv0;  keys[2 + st * 6 + 5] = kv1;
      cur0 = n0; cur1 = n1;
    }
  }
}

// Wp[kb*256+j] = float4{ W[4kb+0][j], ..., W[4kb+3][j] }
__global__ __launch_bounds__(256) void kWp(const float* __restrict__ W, float4* __restrict__ Wp) {
  int idx = blockIdx.x * 256 + threadIdx.x;  // 65536
  int kb = idx >> 8, j = idx & 255;
  float4 w;
  w.x = W[(4 * kb + 0) * 256 + j];
  w.y = W[(4 * kb + 1) * 256 + j];
  w.z = W[(4 * kb + 2) * 256 + j];
  w.w = W[(4 * kb + 3) * 256 + j];
  Wp[idx] = w;
}

// Wtp[kb*256+i] = float4{ W[i][4kb+0], ..., W[i][4kb+3] }
__global__ __launch_bounds__(256) void kWtp(const float* __restrict__ W, float4* __restrict__ Wtp) {
  int idx = blockIdx.x * 256 + threadIdx.x;  // 65536
  int kb = idx >> 8, i = idx & 255;
  float4 w;
  w.x = W[i * 256 + 4 * kb + 0];
  w.y = W[i * 256 + 4 * kb + 1];
  w.z = W[i * 256 + 4 * kb + 2];
  w.w = W[i * 256 + 4 * kb + 3];
  Wtp[idx] = w;
}

__global__ __launch_bounds__(256) void kTf2(const float* __restrict__ fc2w, float* __restrict__ fc2wT) {
  int idx = blockIdx.x * 256 + threadIdx.x;  // 65536
  int k = idx >> 10, o = idx & 1023;
  fc2wT[idx] = fc2w[o * 64 + k];             // fc2wT[k][o]
}

__global__ __launch_bounds__(256) void kX1(const float* __restrict__ cond,
                                           const float* __restrict__ fc1w,
                                           const float* __restrict__ fc1b,
                                           float* __restrict__ x1) {
  int idx = blockIdx.x * 256 + threadIdx.x;  // 524288
  int b = idx >> 6, hh = idx & 63;
  float acc = 0.0f;
  for (int k = 0; k < 16; ++k)
    acc = acc + cond[b * 16 + k] * fc1w[hh * 16 + k];
  acc = acc + fc1b[hh];
  x1[idx] = xla_tanhf(acc);
}

// coalesced via fc2wT; same op order as the passing kMod
__global__ __launch_bounds__(256) void kMod2(const float* __restrict__ x1,
                                             const float* __restrict__ fc2wT,
                                             const float* __restrict__ fc2b,
                                             const float* __restrict__ bvec,
                                             const float* __restrict__ cvec,
                                             float* __restrict__ bmod,
                                             float* __restrict__ cmod) {
  const int bid = blockIdx.x;        // 16384
  const int b = bid >> 1;
  const int half = bid & 1;
  const int ii = threadIdx.x;
  const int og = half * 512 + ii;
  const int ob = og + 256;
  float dg = 0.0f, db = 0.0f;
  for (int k = 0; k < 64; ++k) {
    float xv = x1[b * 64 + k];
    dg = dg + xv * fc2wT[k * 1024 + og];
    db = db + xv * fc2wT[k * 1024 + ob];
  }
  dg = dg + fc2b[og];
  db = db + fc2b[ob];
  float base = half ? cvec[ii] : bvec[ii];
  float outv = (1.0f + dg) * base + db;
  if (half) cmod[b * 256 + ii] = outv;
  else      bmod[b * 256 + ii] = outv;
}

// ================= fused 32-step Gibbs kernel =================
// 512 blocks x 256 threads (4 waves), 16 rows/block, col = threadIdx.x.
// Nw=8 waves/CU: halves W L2 traffic vs R7 at same per-step VALU; the
// 4-wave barrier-synced block shares the W stream through L1.
// All FP op sequences bit-identical to R4/R7 (fma-on-binary exactness).
__global__ __launch_bounds__(256, 2) void kGibbs(
    const float4* __restrict__ Wp, const float4* __restrict__ Wtp,
    const float* __restrict__ bmod, const float* __restrict__ cmod,
    const unsigned* __restrict__ keys, const float* __restrict__ temps,
    float* __restrict__ out) {
  __shared__ float4 X4[16][65];      // veff -> h -> a (row stride 260 floats)
  __shared__ float4 V4[16][65];      // v
  __shared__ float4 BM4[16][65];     // bmod rows
  __shared__ float  chainres[48];
  __shared__ float  bsum_s[16];
  __shared__ int    s0i[16];

  float* Xf  = reinterpret_cast<float*>(X4);
  float* Vf  = reinterpret_cast<float*>(V4);
  float* BMf = reinterpret_cast<float*>(BM4);

  const int j = threadIdx.x;         // 0..255 (column)
  const int brow = blockIdx.x * 16;

  float bmv[16], cmv[16];
  {
    const unsigned k00 = keys[0], k01 = keys[1];
#pragma unroll
    for (int r = 0; r < 16; ++r) {
      const int gi = (brow + r) * 256 + j;
      float bm = bmod[gi];
      bmv[r] = bm; cmv[r] = cmod[gi];
      BMf[r * 260 + j] = bm;
      float u = tf_uniform(k00, k01, (unsigned)gi);
      Vf[r * 260 + j] = (u < 0.5f) ? 1.0f : 0.0f;
    }
  }
  if (j < 16) s0i[j] = 1;
  __syncthreads();
  if (j < 16) {  // bsum per row, sequential ascending plain adds (exact)
    const float* B = BMf + j * 260;
    float s = 0.0f;
    for (int k = 0; k < 256; ++k) s = s + B[k];
    bsum_s[j] = s;
  }

  for (int t = 0; t < kSteps; ++t) {
    const float T = temps[t];
    const unsigned kh0 = keys[2 + t * 6 + 0], kh1 = keys[2 + t * 6 + 1];
    const unsigned ksa = keys[2 + t * 6 + 2], ksb = keys[2 + t * 6 + 3];
    const unsigned kv0 = keys[2 + t * 6 + 4], kv1 = keys[2 + t * 6 + 5];

    // (1) v_eff -> X  (s0 binary: select == s0*v+(1-s0)*(1-v) bit-exact)
#pragma unroll
    for (int r = 0; r < 16; ++r) {
      float vv = Vf[r * 260 + j];
      Xf[r * 260 + j] = s0i[r] ? vv : 1.0f - vv;
    }
    __syncthreads();  // bar1

    // (2) H MAC: acc[r] = sum_k veff[r][k]*W[k][j], ascending k (fma exact)
    float acc[16];
#pragma unroll
    for (int r = 0; r < 16; ++r) acc[r] = 0.0f;
    {
      const float4* wp = Wp + j;
      for (int kb = 0; kb < 64; kb += 4) {
        float4 wa = wp[(kb + 0) << 8];
        float4 wb = wp[(kb + 1) << 8];
        float4 wc = wp[(kb + 2) << 8];
        float4 wd = wp[(kb + 3) << 8];
#pragma unroll
        for (int r = 0; r < 16; ++r) {
          float4 x = X4[r][kb];
          acc[r] = __builtin_fmaf(x.x, wa.x, acc[r]);
          acc[r] = __builtin_fmaf(x.y, wa.y, acc[r]);
          acc[r] = __builtin_fmaf(x.z, wa.z, acc[r]);
          acc[r] = __builtin_fmaf(x.w, wa.w, acc[r]);
        }
#pragma unroll
        for (int r = 0; r < 16; ++r) {
          float4 x = X4[r][kb + 1];
          acc[r] = __builtin_fmaf(x.x, wb.x, acc[r]);
          acc[r] = __builtin_fmaf(x.y, wb.y, acc[r]);
          acc[r] = __builtin_fmaf(x.z, wb.z, acc[r]);
          acc[r] = __builtin_fmaf(x.w, wb.w, acc[r]);
        }
#pragma unroll
        for (int r = 0; r < 16; ++r) {
          float4 x = X4[r][kb + 2];
          acc[r] = __builtin_fmaf(x.x, wc.x, acc[r]);
          acc[r] = __builtin_fmaf(x.y, wc.y, acc[r]);
          acc[r] = __builtin_fmaf(x.z, wc.z, acc[r]);
          acc[r] = __builtin_fmaf(x.w, wc.w, acc[r]);
        }
#pragma unroll
        for (int r = 0; r < 16; ++r) {
          float4 x = X4[r][kb + 3];
          acc[r] = __builtin_fmaf(x.x, wd.x, acc[r]);
          acc[r] = __builtin_fmaf(x.y, wd.y, acc[r]);
          acc[r] = __builtin_fmaf(x.z, wd.z, acc[r]);
          acc[r] = __builtin_fmaf(x.w, wd.w, acc[r]);
        }
      }
    }

    // h draws (regs; before bar2 for overlap)
    float hv[16];
#pragma unroll
    for (int r = 0; r < 16; ++r) {
      float z = (acc[r] + cmv[r]) / T;
      float p = xla_sigmoid(z);
      float u = tf_uniform(kh0, kh1, (unsigned)((brow + r) * 256 + j));
      hv[r] = (u < p) ? 1.0f : 0.0f;
    }
    __syncthreads();  // bar2: all H-MAC reads of X complete
#pragma unroll
    for (int r = 0; r < 16; ++r) Xf[r * 260 + j] = hv[r];
    __syncthreads();  // bar3: h visible

    // (4) AV MAC: acc[r] = sum_k h[r][k]*W[j][k], ascending k (fma exact)
#pragma unroll
    for (int r = 0; r < 16; ++r) acc[r] = 0.0f;
    {
      const float4* wp = Wtp + j;
      for (int kb = 0; kb < 64; kb += 4) {
        float4 wa = wp[(kb + 0) << 8];
        float4 wb = wp[(kb + 1) << 8];
        float4 wc = wp[(kb + 2) << 8];
        float4 wd = wp[(kb + 3) << 8];
#pragma unroll
        for (int r = 0; r < 16; ++r) {
          float4 x = X4[r][kb];
          acc[r] = __builtin_fmaf(x.x, wa.x, acc[r]);
          acc[r] = __builtin_fmaf(x.y, wa.y, acc[r]);
          acc[r] = __builtin_fmaf(x.z, wa.z, acc[r]);
          acc[r] = __builtin_fmaf(x.w, wa.w, acc[r]);
        }
#pragma unroll
        for (int r = 0; r < 16; ++r) {
          float4 x = X4[r][kb + 1];
          acc[r] = __builtin_fmaf(x.x, wb.x, acc[r]);
          acc[r] = __builtin_fmaf(x.y, wb.y, acc[r]);
          acc[r] = __builtin_fmaf(x.z, wb.z, acc[r]);
          acc[r] = __builtin_fmaf(x.w, wb.w, acc[r]);
        }
#pragma unroll
        for (int r = 0; r < 16; ++r) {
          float4 x = X4[r][kb + 2];
          acc[r] = __builtin_fmaf(x.x, wc.x, acc[r]);
          acc[r] = __builtin_fmaf(x.y, wc.y, acc[r]);
          acc[r] = __builtin_fmaf(x.z, wc.z, acc[r]);
          acc[r] = __builtin_fmaf(x.w, wc.w, acc[r]);
        }
#pragma unroll
        for (int r = 0; r < 16; ++r) {
          float4 x = X4[r][kb + 3];
          acc[r] = __builtin_fmaf(x.x, wd.x, acc[r]);
          acc[r] = __builtin_fmaf(x.y, wd.y, acc[r]);
          acc[r] = __builtin_fmaf(x.z, wd.z, acc[r]);
          acc[r] = __builtin_fmaf(x.w, wd.w, acc[r]);
        }
      }
    }

    // v candidate draws (independent of s0)
    float ve2[16];
#pragma unroll
    for (int r = 0; r < 16; ++r) {
      float z = (acc[r] + bmv[r]) / T;
      float p = xla_sigmoid(z);
      float u = tf_uniform(kv0, kv1, (unsigned)((brow + r) * 256 + j));
      ve2[r] = (u < p) ? 1.0f : 0.0f;
    }

    __syncthreads();  // bar4: AV reads of X complete
#pragma unroll
    for (int r = 0; r < 16; ++r) Xf[r * 260 + j] = acc[r];  // spill a
    __syncthreads();  // bar5: a visible

    // chains (lanes 0..47): r=lane/3, c=lane%3; float4 reads
    // c0: vb = sum v*bm; c1: va = sum v*a; c2: as = sum a (ascending, exact)
    if (j < 48) {
      const int r = j / 3, c = j % 3;
      const float4* A4c = reinterpret_cast<const float4*>(Vf + r * 260);
      const float4* Y4c = reinterpret_cast<const float4*>(
          ((c == 0) ? BMf : Xf) + r * 260);
      const bool isAs = (c == 2);
      float s = 0.0f;
      for (int q = 0; q < 64; ++q) {
        float4 a4 = A4c[q];
        float4 y4 = Y4c[q];
        float m0 = isAs ? 1.0f : a4.x; s = __builtin_fmaf(m0, y4.x, s);
        float m1 = isAs ? 1.0f : a4.y; s = __builtin_fmaf(m1, y4.y, s);
        float m2 = isAs ? 1.0f : a4.z; s = __builtin_fmaf(m2, y4.z, s);
        float m3 = isAs ? 1.0f : a4.w; s = __builtin_fmaf(m3, y4.w, s);
      }
      chainres[j] = s;
    }
    __syncthreads();  // bar6

    if (j < 16) {
      const int r = j;
      float vb = chainres[3 * r], va = chainres[3 * r + 1], as = chainres[3 * r + 2];
      float dE = ((-bsum_s[r] - as) + 2.0f * vb) + 2.0f * va;
      float z = dE / T;
      float p = xla_sigmoid(z);
      float u = tf_uniform(ksa, ksb, (unsigned)(brow + r));
      s0i[r] = (u < p) ? 1 : 0;
    }
    __syncthreads();  // bar7

    // v_next = s0 ? ve2 : 1-ve2 (bit-exact select form)
#pragma unroll
    for (int r = 0; r < 16; ++r) {
      Vf[r * 260 + j] = s0i[r] ? ve2[r] : 1.0f - ve2[r];
    }
    __syncthreads();  // bar8
  }

#pragma unroll
  for (int r = 0; r < 16; ++r)
    out[(brow + r) * 256 + j] = Vf[r * 260 + j];
  if (blockIdx.x == 0 && j < 32) out[2097152 + j] = temps[j];
}

}  // namespace

extern "C" void kernel_launch(void* const* d_in, const int* in_sizes, int n_in,
                              void* d_out, int out_size, void* d_ws, size_t ws_size,
                              hipStream_t stream) {
  (void)in_sizes; (void)n_in; (void)out_size;
  const float* cond = (const float*)d_in[0];
  const float* W    = (const float*)d_in[1];
  const float* bvec = (const float*)d_in[2];
  const float* cvec = (const float*)d_in[3];
  const float* fc1w = (const float*)d_in[4];
  const float* fc1b = (const float*)d_in[5];
  const float* fc2w = (const float*)d_in[6];
  const float* fc2b = (const float*)d_in[7];

  if (ws_size < WS_FLOATS * sizeof(float)) return;

  float* ws      = (float*)d_ws;
  float* temps   = ws + OFF_TEMPS;
  unsigned* keys = (unsigned*)(ws + OFF_KEYS);
  float4* Wp     = (float4*)(ws + OFF_WP);
  float4* Wtp    = (float4*)(ws + OFF_WTP);
  float* fc2wT   = ws + OFF_F2T;
  float* x1      = ws + OFF_X1;
  float* bmod    = ws + OFF_BMOD;
  float* cmod    = ws + OFF_CMOD;
  float* out     = (float*)d_out;

  hipLaunchKernelGGL(kInitMeta, dim3(1), dim3(64), 0, stream, temps, keys);
  hipLaunchKernelGGL(kWp, dim3(256), dim3(256), 0, stream, W, Wp);
  hipLaunchKernelGGL(kWtp, dim3(256), dim3(256), 0, stream, W, Wtp);
  hipLaunchKernelGGL(kTf2, dim3(256), dim3(256), 0, stream, fc2w, fc2wT);
  hipLaunchKernelGGL(kX1, dim3(2048), dim3(256), 0, stream, cond, fc1w, fc1b, x1);
  hipLaunchKernelGGL(kMod2, dim3(16384), dim3(256), 0, stream, x1, fc2wT, fc2b, bvec, cvec, bmod, cmod);
  hipLaunchKernelGGL(kGibbs, dim3(512), dim3(256), 0, stream, Wp, Wtp, bmod, cmod, keys, temps, out);
}

// Round 10
// 2344.954 us; speedup vs baseline: 1.2967x; 1.2967x over previous
//
#include <hip/hip_runtime.h>
#include <math.h>

#pragma clang fp contract(off)

namespace {

constexpr int kSteps = 32;

// ---- workspace layout (float slots) ----
constexpr size_t OFF_TEMPS = 0;        // 32 floats
constexpr size_t OFF_KEYS  = 64;       // 194 u32
constexpr size_t OFF_WP    = 512;      // 65536 (float4-packed W)
constexpr size_t OFF_WTP   = 66048;    // 65536 (float4-packed W^T)
constexpr size_t OFF_F2T   = 131584;   // 65536
constexpr size_t OFF_X1    = 197120;   // 524288
constexpr size_t OFF_BMOD  = 721408;   // 2097152
constexpr size_t OFF_CMOD  = 2818560;  // 2097152
constexpr size_t WS_FLOATS = 4915712;  // ~19.7 MB

// ================= threefry2x32 (JAX semantics) =================
__device__ __forceinline__ unsigned rotl32(unsigned v, int n) {
  return (v << n) | (v >> (32 - n));
}

__device__ __forceinline__ void tf_block(unsigned k0, unsigned k1,
                                         unsigned c0, unsigned c1,
                                         unsigned* o0, unsigned* o1) {
  unsigned k2 = k0 ^ k1 ^ 0x1BD11BDAu;
  unsigned x0 = c0 + k0;
  unsigned x1 = c1 + k1;
  x0 += x1; x1 = rotl32(x1, 13); x1 ^= x0;
  x0 += x1; x1 = rotl32(x1, 15); x1 ^= x0;
  x0 += x1; x1 = rotl32(x1, 26); x1 ^= x0;
  x0 += x1; x1 = rotl32(x1, 6);  x1 ^= x0;
  x0 += k1; x1 += k2 + 1u;
  x0 += x1; x1 = rotl32(x1, 17); x1 ^= x0;
  x0 += x1; x1 = rotl32(x1, 29); x1 ^= x0;
  x0 += x1; x1 = rotl32(x1, 16); x1 ^= x0;
  x0 += x1; x1 = rotl32(x1, 24); x1 ^= x0;
  x0 += k2; x1 += k0 + 2u;
  x0 += x1; x1 = rotl32(x1, 13); x1 ^= x0;
  x0 += x1; x1 = rotl32(x1, 15); x1 ^= x0;
  x0 += x1; x1 = rotl32(x1, 26); x1 ^= x0;
  x0 += x1; x1 = rotl32(x1, 6);  x1 ^= x0;
  x0 += k0; x1 += k1 + 3u;
  x0 += x1; x1 = rotl32(x1, 17); x1 ^= x0;
  x0 += x1; x1 = rotl32(x1, 29); x1 ^= x0;
  x0 += x1; x1 = rotl32(x1, 16); x1 ^= x0;
  x0 += x1; x1 = rotl32(x1, 24); x1 ^= x0;
  x0 += k1; x1 += k2 + 4u;
  x0 += x1; x1 = rotl32(x1, 13); x1 ^= x0;
  x0 += x1; x1 = rotl32(x1, 15); x1 ^= x0;
  x0 += x1; x1 = rotl32(x1, 26); x1 ^= x0;
  x0 += x1; x1 = rotl32(x1, 6);  x1 ^= x0;
  x0 += k2; x1 += k0 + 5u;
  *o0 = x0; *o1 = x1;
}

__device__ __forceinline__ float tf_uniform(unsigned k0, unsigned k1, unsigned idx) {
  unsigned o0, o1;
  tf_block(k0, k1, 0u, idx, &o0, &o1);
  unsigned bits = o0 ^ o1;
  float f = __uint_as_float((bits >> 9) | 0x3f800000u);
  return f - 1.0f;
}

// XLA EmitFastTanh (f32), plain mul/add.
__device__ __forceinline__ float xla_tanhf(float x) {
  if (fabsf(x) < 0.0004f) return x;
  float xc = fminf(fmaxf(x, -9.0f), 9.0f);
  float x2 = xc * xc;
  float num = -2.76076847742355e-16f;
  num = num * x2 + 2.00018790482477e-13f;
  num = num * x2 + -8.60467152213735e-11f;
  num = num * x2 + 5.12229709037114e-08f;
  num = num * x2 + 1.48572235717979e-05f;
  num = num * x2 + 6.37261928875436e-04f;
  num = num * x2 + 4.89352455891786e-03f;
  num = xc * num;
  float den = 1.19825839466702e-06f;
  den = den * x2 + 1.18534705686654e-04f;
  den = den * x2 + 2.26843463243900e-03f;
  den = den * x2 + 4.89352518554385e-03f;
  return num / den;
}

// XLA elemental kLogistic: 0.5 + 0.5 * tanh(0.5 * x)
__device__ __forceinline__ float xla_sigmoid(float x) {
  return 0.5f + 0.5f * xla_tanhf(0.5f * x);
}

// ================= setup kernels =================
__global__ __launch_bounds__(64) void kInitMeta(float* temps, unsigned* keys) {
  int t = threadIdx.x;
  if (t < 32) {
    float tf = (float)t;
    float arg = 0.1f * (tf - 16.0f);
    float e = (float)exp((double)arg);  // constant-folded by XLA w/ host expf
    float s = 1.0f / (1.0f + e);
    temps[t] = 1.0f + 4.0f * s;
  }
  if (t == 0) {
    unsigned cur0 = 0u, cur1 = 42u;  // jax.random.key(42)
    unsigned a0, a1, b0, b1;
    tf_block(cur0, cur1, 0u, 0u, &a0, &a1);  // carried key
    tf_block(cur0, cur1, 0u, 1u, &b0, &b1);  // init-v key
    keys[0] = b0; keys[1] = b1;
    cur0 = a0; cur1 = a1;
    for (int st = 0; st < kSteps; ++st) {
      unsigned n0, n1, kh0, kh1, ks0a, ks0b, kv0, kv1;
      tf_block(cur0, cur1, 0u, 0u, &n0, &n1);
      tf_block(cur0, cur1, 0u, 1u, &kh0, &kh1);
      tf_block(cur0, cur1, 0u, 2u, &ks0a, &ks0b);
      tf_block(cur0, cur1, 0u, 3u, &kv0, &kv1);
      keys[2 + st * 6 + 0] = kh0;  keys[2 + st * 6 + 1] = kh1;
      keys[2 + st * 6 + 2] = ks0a; keys[2 + st * 6 + 3] = ks0b;
      keys[2 + st * 6 + 4] = kv0;  keys[2 + st * 6 + 5] = kv1;
      cur0 = n0; cur1 = n1;
    }
  }
}

// Wp[kb*256+j] = float4{ W[4kb+0][j], ..., W[4kb+3][j] }
__global__ __launch_bounds__(256) void kWp(const float* __restrict__ W, float4* __restrict__ Wp) {
  int idx = blockIdx.x * 256 + threadIdx.x;  // 65536
  int kb = idx >> 8, j = idx & 255;
  float4 w;
  w.x = W[(4 * kb + 0) * 256 + j];
  w.y = W[(4 * kb + 1) * 256 + j];
  w.z = W[(4 * kb + 2) * 256 + j];
  w.w = W[(4 * kb + 3) * 256 + j];
  Wp[idx] = w;
}

// Wtp[kb*256+i] = float4{ W[i][4kb+0], ..., W[i][4kb+3] }
__global__ __launch_bounds__(256) void kWtp(const float* __restrict__ W, float4* __restrict__ Wtp) {
  int idx = blockIdx.x * 256 + threadIdx.x;  // 65536
  int kb = idx >> 8, i = idx & 255;
  float4 w;
  w.x = W[i * 256 + 4 * kb + 0];
  w.y = W[i * 256 + 4 * kb + 1];
  w.z = W[i * 256 + 4 * kb + 2];
  w.w = W[i * 256 + 4 * kb + 3];
  Wtp[idx] = w;
}

__global__ __launch_bounds__(256) void kTf2(const float* __restrict__ fc2w, float* __restrict__ fc2wT) {
  int idx = blockIdx.x * 256 + threadIdx.x;  // 65536
  int k = idx >> 10, o = idx & 1023;
  fc2wT[idx] = fc2w[o * 64 + k];             // fc2wT[k][o]
}

__global__ __launch_bounds__(256) void kX1(const float* __restrict__ cond,
                                           const float* __restrict__ fc1w,
                                           const float* __restrict__ fc1b,
                                           float* __restrict__ x1) {
  int idx = blockIdx.x * 256 + threadIdx.x;  // 524288
  int b = idx >> 6, hh = idx & 63;
  float acc = 0.0f;
  for (int k = 0; k < 16; ++k)
    acc = acc + cond[b * 16 + k] * fc1w[hh * 16 + k];
  acc = acc + fc1b[hh];
  x1[idx] = xla_tanhf(acc);
}

// coalesced via fc2wT; same op order as the passing kMod
__global__ __launch_bounds__(256) void kMod2(const float* __restrict__ x1,
                                             const float* __restrict__ fc2wT,
                                             const float* __restrict__ fc2b,
                                             const float* __restrict__ bvec,
                                             const float* __restrict__ cvec,
                                             float* __restrict__ bmod,
                                             float* __restrict__ cmod) {
  const int bid = blockIdx.x;        // 16384
  const int b = bid >> 1;
  const int half = bid & 1;
  const int ii = threadIdx.x;
  const int og = half * 512 + ii;
  const int ob = og + 256;
  float dg = 0.0f, db = 0.0f;
  for (int k = 0; k < 64; ++k) {
    float xv = x1[b * 64 + k];
    dg = dg + xv * fc2wT[k * 1024 + og];
    db = db + xv * fc2wT[k * 1024 + ob];
  }
  dg = dg + fc2b[og];
  db = db + fc2b[ob];
  float base = half ? cvec[ii] : bvec[ii];
  float outv = (1.0f + dg) * base + db;
  if (half) cmod[b * 256 + ii] = outv;
  else      bmod[b * 256 + ii] = outv;
}

// ================= fused 32-step Gibbs kernel =================
// 2048 blocks x 256 threads (4 waves), 4 rows/block, col = threadIdx.x.
// Target 32 waves/CU (8 blocks/CU) for stall hiding — R5/R8/R9 showed
// <16 waves/CU loses; R4/R7 at 16 were ~39% SIMD-utilized (stall-bound).
// 6 barriers/step: veff(t+1)==ve2 (double-flip on binary, bit-exact) is
// written to X right after bar4; a-spill gets its own A4 buffer.
// All FP op sequences bit-identical to R4/R7 (fma-on-binary exactness).
__global__ __launch_bounds__(256, 6) void kGibbs(
    const float4* __restrict__ Wp, const float4* __restrict__ Wtp,
    const float* __restrict__ bmod, const float* __restrict__ cmod,
    const unsigned* __restrict__ keys, const float* __restrict__ temps,
    float* __restrict__ out) {
  __shared__ float4 X4[4][65];       // veff(t) -> h -> veff(t+1)=ve2
  __shared__ float4 A4[4][65];       // a spill (chains)
  __shared__ float4 V4[4][65];       // v
  __shared__ float4 BM4[4][65];      // bmod rows
  __shared__ float  chainres[12];
  __shared__ float  bsum_s[4];
  __shared__ int    s0i[4];

  float* Xf  = reinterpret_cast<float*>(X4);
  float* Af  = reinterpret_cast<float*>(A4);
  float* Vf  = reinterpret_cast<float*>(V4);
  float* BMf = reinterpret_cast<float*>(BM4);

  const int j = threadIdx.x;         // 0..255 (column)
  const int brow = blockIdx.x * 4;

  float bmv[4], cmv[4];
  {
    const unsigned k00 = keys[0], k01 = keys[1];
#pragma unroll
    for (int r = 0; r < 4; ++r) {
      const int gi = (brow + r) * 256 + j;
      float bm = bmod[gi];
      bmv[r] = bm; cmv[r] = cmod[gi];
      BMf[r * 260 + j] = bm;
      float u = tf_uniform(k00, k01, (unsigned)gi);
      float vv = (u < 0.5f) ? 1.0f : 0.0f;
      Vf[r * 260 + j] = vv;
      Xf[r * 260 + j] = vv;          // veff at t=0 (s0=1)
    }
  }
  if (j < 4) s0i[j] = 1;
  __syncthreads();
  if (j < 4) {  // bsum per row, sequential ascending plain adds (exact);
                // read at step-0 bar6 by the same lanes -> no extra barrier
    const float* B = BMf + j * 260;
    float s = 0.0f;
    for (int k = 0; k < 256; ++k) s = s + B[k];
    bsum_s[j] = s;
  }

  for (int t = 0; t < kSteps; ++t) {
    const float T = temps[t];
    const unsigned kh0 = keys[2 + t * 6 + 0], kh1 = keys[2 + t * 6 + 1];
    const unsigned ksa = keys[2 + t * 6 + 2], ksb = keys[2 + t * 6 + 3];
    const unsigned kv0 = keys[2 + t * 6 + 4], kv1 = keys[2 + t * 6 + 5];

    // (1) H MAC: acc[r] = sum_k veff[r][k]*W[k][j], ascending k (fma exact)
    float acc[4];
#pragma unroll
    for (int r = 0; r < 4; ++r) acc[r] = 0.0f;
    {
      const float4* wp = Wp + j;
      for (int kb = 0; kb < 64; ++kb) {
        float4 w = wp[kb << 8];
#pragma unroll
        for (int r = 0; r < 4; ++r) {
          float4 x = X4[r][kb];
          acc[r] = __builtin_fmaf(x.x, w.x, acc[r]);
          acc[r] = __builtin_fmaf(x.y, w.y, acc[r]);
          acc[r] = __builtin_fmaf(x.z, w.z, acc[r]);
          acc[r] = __builtin_fmaf(x.w, w.w, acc[r]);
        }
      }
    }

    // h draws (regs; before bar2 for overlap)
    float hv[4];
#pragma unroll
    for (int r = 0; r < 4; ++r) {
      float z = (acc[r] + cmv[r]) / T;
      float p = xla_sigmoid(z);
      float u = tf_uniform(kh0, kh1, (unsigned)((brow + r) * 256 + j));
      hv[r] = (u < p) ? 1.0f : 0.0f;
    }
    __syncthreads();  // bar2: all H-MAC reads of X complete
#pragma unroll
    for (int r = 0; r < 4; ++r) Xf[r * 260 + j] = hv[r];
    __syncthreads();  // bar3: h visible

    // (2) AV MAC: acc[r] = sum_k h[r][k]*W[j][k], ascending k (fma exact)
#pragma unroll
    for (int r = 0; r < 4; ++r) acc[r] = 0.0f;
    {
      const float4* wp = Wtp + j;
      for (int kb = 0; kb < 64; ++kb) {
        float4 w = wp[kb << 8];
#pragma unroll
        for (int r = 0; r < 4; ++r) {
          float4 x = X4[r][kb];
          acc[r] = __builtin_fmaf(x.x, w.x, acc[r]);
          acc[r] = __builtin_fmaf(x.y, w.y, acc[r]);
          acc[r] = __builtin_fmaf(x.z, w.z, acc[r]);
          acc[r] = __builtin_fmaf(x.w, w.w, acc[r]);
        }
      }
    }

    // v candidate draws (independent of s0)
    float ve2[4];
#pragma unroll
    for (int r = 0; r < 4; ++r) {
      float z = (acc[r] + bmv[r]) / T;
      float p = xla_sigmoid(z);
      float u = tf_uniform(kv0, kv1, (unsigned)((brow + r) * 256 + j));
      ve2[r] = (u < p) ? 1.0f : 0.0f;
    }

    __syncthreads();  // bar4: AV reads of X complete
#pragma unroll
    for (int r = 0; r < 4; ++r) {
      Af[r * 260 + j] = acc[r];      // a -> A4 (chains)
      Xf[r * 260 + j] = ve2[r];      // veff(t+1) == ve2 (double-flip, exact)
    }
    __syncthreads();  // bar5: a + next-veff visible

    // chains (lanes 0..11, all wave 0): r=lane/3, c=lane%3; float4 reads
    // c0: vb = sum v*bm; c1: va = sum v*a; c2: as = sum a (ascending, exact)
    if (j < 12) {
      const int r = j / 3, c = j % 3;
      const float4* A4c = reinterpret_cast<const float4*>(Vf + r * 260);
      const float4* Y4c = reinterpret_cast<const float4*>(
          ((c == 0) ? BMf : Af) + r * 260);
      const bool isAs = (c == 2);
      float s = 0.0f;
      for (int q = 0; q < 64; ++q) {
        float4 a4 = A4c[q];
        float4 y4 = Y4c[q];
        float m0 = isAs ? 1.0f : a4.x; s = __builtin_fmaf(m0, y4.x, s);
        float m1 = isAs ? 1.0f : a4.y; s = __builtin_fmaf(m1, y4.y, s);
        float m2 = isAs ? 1.0f : a4.z; s = __builtin_fmaf(m2, y4.z, s);
        float m3 = isAs ? 1.0f : a4.w; s = __builtin_fmaf(m3, y4.w, s);
      }
      chainres[j] = s;
    }
    __syncthreads();  // bar6

    if (j < 4) {
      const int r = j;
      float vb = chainres[3 * r], va = chainres[3 * r + 1], as = chainres[3 * r + 2];
      float dE = ((-bsum_s[r] - as) + 2.0f * vb) + 2.0f * va;
      float z = dE / T;
      float p = xla_sigmoid(z);
      float u = tf_uniform(ksa, ksb, (unsigned)(brow + r));
      s0i[r] = (u < p) ? 1 : 0;
    }
    __syncthreads();  // bar7

    // v_next = s0 ? ve2 : 1-ve2 (bit-exact select form). Next chains read
    // Vf only after bar5(t+1), so no trailing barrier needed.
#pragma unroll
    for (int r = 0; r < 4; ++r) {
      Vf[r * 260 + j] = s0i[r] ? ve2[r] : 1.0f - ve2[r];
    }
  }

#pragma unroll
  for (int r = 0; r < 4; ++r)
    out[(brow + r) * 256 + j] = Vf[r * 260 + j];   // own writes, no race
  if (blockIdx.x == 0 && j < 32) out[2097152 + j] = temps[j];
}

}  // namespace

extern "C" void kernel_launch(void* const* d_in, const int* in_sizes, int n_in,
                              void* d_out, int out_size, void* d_ws, size_t ws_size,
                              hipStream_t stream) {
  (void)in_sizes; (void)n_in; (void)out_size;
  const float* cond = (const float*)d_in[0];
  const float* W    = (const float*)d_in[1];
  const float* bvec = (const float*)d_in[2];
  const float* cvec = (const float*)d_in[3];
  const float* fc1w = (const float*)d_in[4];
  const float* fc1b = (const float*)d_in[5];
  const float* fc2w = (const float*)d_in[6];
  const float* fc2b = (const float*)d_in[7];

  if (ws_size < WS_FLOATS * sizeof(float)) return;

  float* ws      = (float*)d_ws;
  float* temps   = ws + OFF_TEMPS;
  unsigned* keys = (unsigned*)(ws + OFF_KEYS);
  float4* Wp     = (float4*)(ws + OFF_WP);
  float4* Wtp    = (float4*)(ws + OFF_WTP);
  float* fc2wT   = ws + OFF_F2T;
  float* x1      = ws + OFF_X1;
  float* bmod    = ws + OFF_BMOD;
  float* cmod    = ws + OFF_CMOD;
  float* out     = (float*)d_out;

  hipLaunchKernelGGL(kInitMeta, dim3(1), dim3(64), 0, stream, temps, keys);
  hipLaunchKernelGGL(kWp, dim3(256), dim3(256), 0, stream, W, Wp);
  hipLaunchKernelGGL(kWtp, dim3(256), dim3(256), 0, stream, W, Wtp);
  hipLaunchKernelGGL(kTf2, dim3(256), dim3(256), 0, stream, fc2w, fc2wT);
  hipLaunchKernelGGL(kX1, dim3(2048), dim3(256), 0, stream, cond, fc1w, fc1b, x1);
  hipLaunchKernelGGL(kMod2, dim3(16384), dim3(256), 0, stream, x1, fc2wT, fc2b, bvec, cvec, bmod, cmod);
  hipLaunchKernelGGL(kGibbs, dim3(2048), dim3(256), 0, stream, Wp, Wtp, bmod, cmod, keys, temps, out);
}

// Round 11
// 1781.948 us; speedup vs baseline: 1.7064x; 1.3159x over previous
//
#include <hip/hip_runtime.h>
#include <math.h>

#pragma clang fp contract(off)

namespace {

constexpr int kSteps = 32;

// ---- workspace layout (float slots) ----
constexpr size_t OFF_TEMPS = 0;        // 32 floats
constexpr size_t OFF_KEYS  = 64;       // 194 u32
constexpr size_t OFF_WP    = 512;      // 65536 (float4-packed W)
constexpr size_t OFF_WTP   = 66048;    // 65536 (float4-packed W^T)
constexpr size_t OFF_F2T   = 131584;   // 65536
constexpr size_t OFF_X1    = 197120;   // 524288
constexpr size_t OFF_BMOD  = 721408;   // 2097152
constexpr size_t OFF_CMOD  = 2818560;  // 2097152
constexpr size_t WS_FLOATS = 4915712;  // ~19.7 MB

// ================= threefry2x32 (JAX semantics) =================
__device__ __forceinline__ unsigned rotl32(unsigned v, int n) {
  return (v << n) | (v >> (32 - n));
}

__device__ __forceinline__ void tf_block(unsigned k0, unsigned k1,
                                         unsigned c0, unsigned c1,
                                         unsigned* o0, unsigned* o1) {
  unsigned k2 = k0 ^ k1 ^ 0x1BD11BDAu;
  unsigned x0 = c0 + k0;
  unsigned x1 = c1 + k1;
  x0 += x1; x1 = rotl32(x1, 13); x1 ^= x0;
  x0 += x1; x1 = rotl32(x1, 15); x1 ^= x0;
  x0 += x1; x1 = rotl32(x1, 26); x1 ^= x0;
  x0 += x1; x1 = rotl32(x1, 6);  x1 ^= x0;
  x0 += k1; x1 += k2 + 1u;
  x0 += x1; x1 = rotl32(x1, 17); x1 ^= x0;
  x0 += x1; x1 = rotl32(x1, 29); x1 ^= x0;
  x0 += x1; x1 = rotl32(x1, 16); x1 ^= x0;
  x0 += x1; x1 = rotl32(x1, 24); x1 ^= x0;
  x0 += k2; x1 += k0 + 2u;
  x0 += x1; x1 = rotl32(x1, 13); x1 ^= x0;
  x0 += x1; x1 = rotl32(x1, 15); x1 ^= x0;
  x0 += x1; x1 = rotl32(x1, 26); x1 ^= x0;
  x0 += x1; x1 = rotl32(x1, 6);  x1 ^= x0;
  x0 += k0; x1 += k1 + 3u;
  x0 += x1; x1 = rotl32(x1, 17); x1 ^= x0;
  x0 += x1; x1 = rotl32(x1, 29); x1 ^= x0;
  x0 += x1; x1 = rotl32(x1, 16); x1 ^= x0;
  x0 += x1; x1 = rotl32(x1, 24); x1 ^= x0;
  x0 += k1; x1 += k2 + 4u;
  x0 += x1; x1 = rotl32(x1, 13); x1 ^= x0;
  x0 += x1; x1 = rotl32(x1, 15); x1 ^= x0;
  x0 += x1; x1 = rotl32(x1, 26); x1 ^= x0;
  x0 += x1; x1 = rotl32(x1, 6);  x1 ^= x0;
  x0 += k2; x1 += k0 + 5u;
  *o0 = x0; *o1 = x1;
}

__device__ __forceinline__ float tf_uniform(unsigned k0, unsigned k1, unsigned idx) {
  unsigned o0, o1;
  tf_block(k0, k1, 0u, idx, &o0, &o1);
  unsigned bits = o0 ^ o1;
  float f = __uint_as_float((bits >> 9) | 0x3f800000u);
  return f - 1.0f;
}

// XLA EmitFastTanh (f32), plain mul/add.
__device__ __forceinline__ float xla_tanhf(float x) {
  if (fabsf(x) < 0.0004f) return x;
  float xc = fminf(fmaxf(x, -9.0f), 9.0f);
  float x2 = xc * xc;
  float num = -2.76076847742355e-16f;
  num = num * x2 + 2.00018790482477e-13f;
  num = num * x2 + -8.60467152213735e-11f;
  num = num * x2 + 5.12229709037114e-08f;
  num = num * x2 + 1.48572235717979e-05f;
  num = num * x2 + 6.37261928875436e-04f;
  num = num * x2 + 4.89352455891786e-03f;
  num = xc * num;
  float den = 1.19825839466702e-06f;
  den = den * x2 + 1.18534705686654e-04f;
  den = den * x2 + 2.26843463243900e-03f;
  den = den * x2 + 4.89352518554385e-03f;
  return num / den;
}

// XLA elemental kLogistic: 0.5 + 0.5 * tanh(0.5 * x)
__device__ __forceinline__ float xla_sigmoid(float x) {
  return 0.5f + 0.5f * xla_tanhf(0.5f * x);
}

// ================= setup kernels =================
__global__ __launch_bounds__(64) void kInitMeta(float* temps, unsigned* keys) {
  int t = threadIdx.x;
  if (t < 32) {
    float tf = (float)t;
    float arg = 0.1f * (tf - 16.0f);
    float e = (float)exp((double)arg);  // constant-folded by XLA w/ host expf
    float s = 1.0f / (1.0f + e);
    temps[t] = 1.0f + 4.0f * s;
  }
  if (t == 0) {
    unsigned cur0 = 0u, cur1 = 42u;  // jax.random.key(42)
    unsigned a0, a1, b0, b1;
    tf_block(cur0, cur1, 0u, 0u, &a0, &a1);  // carried key
    tf_block(cur0, cur1, 0u, 1u, &b0, &b1);  // init-v key
    keys[0] = b0; keys[1] = b1;
    cur0 = a0; cur1 = a1;
    for (int st = 0; st < kSteps; ++st) {
      unsigned n0, n1, kh0, kh1, ks0a, ks0b, kv0, kv1;
      tf_block(cur0, cur1, 0u, 0u, &n0, &n1);
      tf_block(cur0, cur1, 0u, 1u, &kh0, &kh1);
      tf_block(cur0, cur1, 0u, 2u, &ks0a, &ks0b);
      tf_block(cur0, cur1, 0u, 3u, &kv0, &kv1);
      keys[2 + st * 6 + 0] = kh0;  keys[2 + st * 6 + 1] = kh1;
      keys[2 + st * 6 + 2] = ks0a; keys[2 + st * 6 + 3] = ks0b;
      keys[2 + st * 6 + 4] = kv0;  keys[2 + st * 6 + 5] = kv1;
      cur0 = n0; cur1 = n1;
    }
  }
}

// Wp[kb*256+j] = float4{ W[4kb+0][j], ..., W[4kb+3][j] }
__global__ __launch_bounds__(256) void kWp(const float* __restrict__ W, float4* __restrict__ Wp) {
  int idx = blockIdx.x * 256 + threadIdx.x;  // 65536
  int kb = idx >> 8, j = idx & 255;
  float4 w;
  w.x = W[(4 * kb + 0) * 256 + j];
  w.y = W[(4 * kb + 1) * 256 + j];
  w.z = W[(4 * kb + 2) * 256 + j];
  w.w = W[(4 * kb + 3) * 256 + j];
  Wp[idx] = w;
}

// Wtp[kb*256+i] = float4{ W[i][4kb+0], ..., W[i][4kb+3] }
__global__ __launch_bounds__(256) void kWtp(const float* __restrict__ W, float4* __restrict__ Wtp) {
  int idx = blockIdx.x * 256 + threadIdx.x;  // 65536
  int kb = idx >> 8, i = idx & 255;
  float4 w;
  w.x = W[i * 256 + 4 * kb + 0];
  w.y = W[i * 256 + 4 * kb + 1];
  w.z = W[i * 256 + 4 * kb + 2];
  w.w = W[i * 256 + 4 * kb + 3];
  Wtp[idx] = w;
}

__global__ __launch_bounds__(256) void kTf2(const float* __restrict__ fc2w, float* __restrict__ fc2wT) {
  int idx = blockIdx.x * 256 + threadIdx.x;  // 65536
  int k = idx >> 10, o = idx & 1023;
  fc2wT[idx] = fc2w[o * 64 + k];             // fc2wT[k][o]
}

__global__ __launch_bounds__(256) void kX1(const float* __restrict__ cond,
                                           const float* __restrict__ fc1w,
                                           const float* __restrict__ fc1b,
                                           float* __restrict__ x1) {
  int idx = blockIdx.x * 256 + threadIdx.x;  // 524288
  int b = idx >> 6, hh = idx & 63;
  float acc = 0.0f;
  for (int k = 0; k < 16; ++k)
    acc = acc + cond[b * 16 + k] * fc1w[hh * 16 + k];
  acc = acc + fc1b[hh];
  x1[idx] = xla_tanhf(acc);
}

// coalesced via fc2wT; same op order as the passing kMod
__global__ __launch_bounds__(256) void kMod2(const float* __restrict__ x1,
                                             const float* __restrict__ fc2wT,
                                             const float* __restrict__ fc2b,
                                             const float* __restrict__ bvec,
                                             const float* __restrict__ cvec,
                                             float* __restrict__ bmod,
                                             float* __restrict__ cmod) {
  const int bid = blockIdx.x;        // 16384
  const int b = bid >> 1;
  const int half = bid & 1;
  const int ii = threadIdx.x;
  const int og = half * 512 + ii;
  const int ob = og + 256;
  float dg = 0.0f, db = 0.0f;
  for (int k = 0; k < 64; ++k) {
    float xv = x1[b * 64 + k];
    dg = dg + xv * fc2wT[k * 1024 + og];
    db = db + xv * fc2wT[k * 1024 + ob];
  }
  dg = dg + fc2b[og];
  db = db + fc2b[ob];
  float base = half ? cvec[ii] : bvec[ii];
  float outv = (1.0f + dg) * base + db;
  if (half) cmod[b * 256 + ii] = outv;
  else      bmod[b * 256 + ii] = outv;
}

// ================= fused 32-step Gibbs kernel =================
// R7 geometry (2048 blocks x 128 threads, 4 rows, cols j0/j0+128 per thread;
// 16 waves/CU) -- the measured optimum of the {LDS-broadcast ~ T, W-L2 ~
// waves*C, VALU fixed} tradeoff -- plus R10's verified 6-barrier structure:
// veff(t+1)==ve2 (double-flip on binary, bit-exact) folded into the post-AV
// write, dedicated A4 spill buffer. MAC kb-loop unrolled x2 with named
// W prefetch vars (no arrays -> no scratch, R6 lesson).
// All FP op sequences bit-identical to R7/R10 (fma-on-binary exactness).
__global__ __launch_bounds__(128, 4) void kGibbs(
    const float4* __restrict__ Wp, const float4* __restrict__ Wtp,
    const float* __restrict__ bmod, const float* __restrict__ cmod,
    const unsigned* __restrict__ keys, const float* __restrict__ temps,
    float* __restrict__ out) {
  __shared__ float4 X4[4][65];       // veff(t) -> h -> veff(t+1)=ve2
  __shared__ float4 A4[4][65];       // a spill (chains)
  __shared__ float4 V4[4][65];       // v
  __shared__ float4 BM4[4][65];      // bmod rows
  __shared__ float  chainres[12];
  __shared__ float  bsum_s[4];
  __shared__ int    s0i[4];

  float* Xf  = reinterpret_cast<float*>(X4);
  float* Af  = reinterpret_cast<float*>(A4);
  float* Vf  = reinterpret_cast<float*>(V4);
  float* BMf = reinterpret_cast<float*>(BM4);

  const int j0 = threadIdx.x;        // 0..127
  const int j1 = j0 + 128;
  const int brow = blockIdx.x * 4;

  float bmv[4][2], cmv[4][2];
  {
    const unsigned k00 = keys[0], k01 = keys[1];
#pragma unroll
    for (int r = 0; r < 4; ++r) {
      const int g0 = (brow + r) * 256 + j0;
      const int g1 = g0 + 128;
      float bm0 = bmod[g0], bm1 = bmod[g1];
      bmv[r][0] = bm0; bmv[r][1] = bm1;
      cmv[r][0] = cmod[g0]; cmv[r][1] = cmod[g1];
      BMf[r * 260 + j0] = bm0;
      BMf[r * 260 + j1] = bm1;
      float u0 = tf_uniform(k00, k01, (unsigned)g0);
      float u1 = tf_uniform(k00, k01, (unsigned)g1);
      float v0 = (u0 < 0.5f) ? 1.0f : 0.0f;
      float v1 = (u1 < 0.5f) ? 1.0f : 0.0f;
      Vf[r * 260 + j0] = v0;
      Vf[r * 260 + j1] = v1;
      Xf[r * 260 + j0] = v0;         // veff at t=0 (s0=1)
      Xf[r * 260 + j1] = v1;
    }
  }
  if (j0 < 4) s0i[j0] = 1;
  __syncthreads();
  if (j0 < 4) {  // bsum per row, sequential ascending plain adds (exact);
                 // read later by the same lanes (s0 section) -> safe
    const float* B = BMf + j0 * 260;
    float s = 0.0f;
    for (int k = 0; k < 256; ++k) s = s + B[k];
    bsum_s[j0] = s;
  }

  for (int t = 0; t < kSteps; ++t) {
    const float T = temps[t];
    const unsigned kh0 = keys[2 + t * 6 + 0], kh1 = keys[2 + t * 6 + 1];
    const unsigned ksa = keys[2 + t * 6 + 2], ksb = keys[2 + t * 6 + 3];
    const unsigned kv0 = keys[2 + t * 6 + 4], kv1 = keys[2 + t * 6 + 5];

    // ---- H MAC: acc[r][c] = sum_k veff[r][k]*W[k][col], ascending k ----
    float a0[4], a1[4];
#pragma unroll
    for (int r = 0; r < 4; ++r) { a0[r] = 0.0f; a1[r] = 0.0f; }
    {
      const float4* wpa = Wp + j0;
      const float4* wpb = Wp + j1;
      for (int kb = 0; kb < 64; kb += 2) {
        float4 wa0 = wpa[(kb + 0) << 8];
        float4 wb0 = wpb[(kb + 0) << 8];
        float4 wa1 = wpa[(kb + 1) << 8];
        float4 wb1 = wpb[(kb + 1) << 8];
#pragma unroll
        for (int r = 0; r < 4; ++r) {
          float4 x = X4[r][kb];
          a0[r] = __builtin_fmaf(x.x, wa0.x, a0[r]);
          a0[r] = __builtin_fmaf(x.y, wa0.y, a0[r]);
          a0[r] = __builtin_fmaf(x.z, wa0.z, a0[r]);
          a0[r] = __builtin_fmaf(x.w, wa0.w, a0[r]);
          a1[r] = __builtin_fmaf(x.x, wb0.x, a1[r]);
          a1[r] = __builtin_fmaf(x.y, wb0.y, a1[r]);
          a1[r] = __builtin_fmaf(x.z, wb0.z, a1[r]);
          a1[r] = __builtin_fmaf(x.w, wb0.w, a1[r]);
        }
#pragma unroll
        for (int r = 0; r < 4; ++r) {
          float4 x = X4[r][kb + 1];
          a0[r] = __builtin_fmaf(x.x, wa1.x, a0[r]);
          a0[r] = __builtin_fmaf(x.y, wa1.y, a0[r]);
          a0[r] = __builtin_fmaf(x.z, wa1.z, a0[r]);
          a0[r] = __builtin_fmaf(x.w, wa1.w, a0[r]);
          a1[r] = __builtin_fmaf(x.x, wb1.x, a1[r]);
          a1[r] = __builtin_fmaf(x.y, wb1.y, a1[r]);
          a1[r] = __builtin_fmaf(x.z, wb1.z, a1[r]);
          a1[r] = __builtin_fmaf(x.w, wb1.w, a1[r]);
        }
      }
    }

    // h draws (regs only; before bar2 for overlap)
    float hv0[4], hv1[4];
#pragma unroll
    for (int r = 0; r < 4; ++r) {
      const int g0 = (brow + r) * 256 + j0;
      float z0 = (a0[r] + cmv[r][0]) / T;
      float p0 = xla_sigmoid(z0);
      float u0 = tf_uniform(kh0, kh1, (unsigned)g0);
      hv0[r] = (u0 < p0) ? 1.0f : 0.0f;
      float z1 = (a1[r] + cmv[r][1]) / T;
      float p1 = xla_sigmoid(z1);
      float u1 = tf_uniform(kh0, kh1, (unsigned)(g0 + 128));
      hv1[r] = (u1 < p1) ? 1.0f : 0.0f;
    }
    __syncthreads();  // bar2: all H-MAC reads of X complete
#pragma unroll
    for (int r = 0; r < 4; ++r) {
      Xf[r * 260 + j0] = hv0[r];
      Xf[r * 260 + j1] = hv1[r];
    }
    __syncthreads();  // bar3: h visible

    // ---- AV MAC: acc[r][c] = sum_k h[r][k]*W[col][k], ascending k ----
#pragma unroll
    for (int r = 0; r < 4; ++r) { a0[r] = 0.0f; a1[r] = 0.0f; }
    {
      const float4* wpa = Wtp + j0;
      const float4* wpb = Wtp + j1;
      for (int kb = 0; kb < 64; kb += 2) {
        float4 wa0 = wpa[(kb + 0) << 8];
        float4 wb0 = wpb[(kb + 0) << 8];
        float4 wa1 = wpa[(kb + 1) << 8];
        float4 wb1 = wpb[(kb + 1) << 8];
#pragma unroll
        for (int r = 0; r < 4; ++r) {
          float4 x = X4[r][kb];
          a0[r] = __builtin_fmaf(x.x, wa0.x, a0[r]);
          a0[r] = __builtin_fmaf(x.y, wa0.y, a0[r]);
          a0[r] = __builtin_fmaf(x.z, wa0.z, a0[r]);
          a0[r] = __builtin_fmaf(x.w, wa0.w, a0[r]);
          a1[r] = __builtin_fmaf(x.x, wb0.x, a1[r]);
          a1[r] = __builtin_fmaf(x.y, wb0.y, a1[r]);
          a1[r] = __builtin_fmaf(x.z, wb0.z, a1[r]);
          a1[r] = __builtin_fmaf(x.w, wb0.w, a1[r]);
        }
#pragma unroll
        for (int r = 0; r < 4; ++r) {
          float4 x = X4[r][kb + 1];
          a0[r] = __builtin_fmaf(x.x, wa1.x, a0[r]);
          a0[r] = __builtin_fmaf(x.y, wa1.y, a0[r]);
          a0[r] = __builtin_fmaf(x.z, wa1.z, a0[r]);
          a0[r] = __builtin_fmaf(x.w, wa1.w, a0[r]);
          a1[r] = __builtin_fmaf(x.x, wb1.x, a1[r]);
          a1[r] = __builtin_fmaf(x.y, wb1.y, a1[r]);
          a1[r] = __builtin_fmaf(x.z, wb1.z, a1[r]);
          a1[r] = __builtin_fmaf(x.w, wb1.w, a1[r]);
        }
      }
    }

    // v candidate draws (independent of s0)
    float ve20[4], ve21[4];
#pragma unroll
    for (int r = 0; r < 4; ++r) {
      const int g0 = (brow + r) * 256 + j0;
      float z0 = (a0[r] + bmv[r][0]) / T;
      float p0 = xla_sigmoid(z0);
      float u0 = tf_uniform(kv0, kv1, (unsigned)g0);
      ve20[r] = (u0 < p0) ? 1.0f : 0.0f;
      float z1 = (a1[r] + bmv[r][1]) / T;
      float p1 = xla_sigmoid(z1);
      float u1 = tf_uniform(kv0, kv1, (unsigned)(g0 + 128));
      ve21[r] = (u1 < p1) ? 1.0f : 0.0f;
    }

    __syncthreads();  // bar4: AV reads of X complete
#pragma unroll
    for (int r = 0; r < 4; ++r) {
      Af[r * 260 + j0] = a0[r];      // a -> A4 (chains)
      Af[r * 260 + j1] = a1[r];
      Xf[r * 260 + j0] = ve20[r];    // veff(t+1) == ve2 (double-flip, exact)
      Xf[r * 260 + j1] = ve21[r];
    }
    __syncthreads();  // bar5: a + next-veff visible

    // chains (lanes 0..11, wave 0): r=lane/3, c=lane%3; float4 reads
    // c0: vb = sum v*bm; c1: va = sum v*a; c2: as = sum a (ascending, exact)
    if (j0 < 12) {
      const int r = j0 / 3, c = j0 % 3;
      const float4* A4c = reinterpret_cast<const float4*>(Vf + r * 260);
      const float4* Y4c = reinterpret_cast<const float4*>(
          ((c == 0) ? BMf : Af) + r * 260);
      const bool isAs = (c == 2);
      float s = 0.0f;
      for (int q = 0; q < 64; ++q) {
        float4 a4 = A4c[q];
        float4 y4 = Y4c[q];
        float m0 = isAs ? 1.0f : a4.x; s = __builtin_fmaf(m0, y4.x, s);
        float m1 = isAs ? 1.0f : a4.y; s = __builtin_fmaf(m1, y4.y, s);
        float m2 = isAs ? 1.0f : a4.z; s = __builtin_fmaf(m2, y4.z, s);
        float m3 = isAs ? 1.0f : a4.w; s = __builtin_fmaf(m3, y4.w, s);
      }
      chainres[j0] = s;
    }
    __syncthreads();  // bar6

    if (j0 < 4) {
      const int r = j0;
      float vb = chainres[3 * r], va = chainres[3 * r + 1], as = chainres[3 * r + 2];
      float dE = ((-bsum_s[r] - as) + 2.0f * vb) + 2.0f * va;
      float z = dE / T;
      float p = xla_sigmoid(z);
      float u = tf_uniform(ksa, ksb, (unsigned)(brow + r));
      s0i[r] = (u < p) ? 1 : 0;
    }
    __syncthreads();  // bar7

    // v_next = s0 ? ve2 : 1-ve2 (bit-exact select form). Next reads of Vf
    // (chains at t+1) are after bar5(t+1) -> ordering safe, no trailing bar.
#pragma unroll
    for (int r = 0; r < 4; ++r) {
      Vf[r * 260 + j0] = s0i[r] ? ve20[r] : 1.0f - ve20[r];
      Vf[r * 260 + j1] = s0i[r] ? ve21[r] : 1.0f - ve21[r];
    }
  }

  __syncthreads();
#pragma unroll
  for (int r = 0; r < 4; ++r) {
    out[(brow + r) * 256 + j0] = Vf[r * 260 + j0];
    out[(brow + r) * 256 + j1] = Vf[r * 260 + j1];
  }
  if (blockIdx.x == 0 && j0 < 32) out[2097152 + j0] = temps[j0];
}

}  // namespace

extern "C" void kernel_launch(void* const* d_in, const int* in_sizes, int n_in,
                              void* d_out, int out_size, void* d_ws, size_t ws_size,
                              hipStream_t stream) {
  (void)in_sizes; (void)n_in; (void)out_size;
  const float* cond = (const float*)d_in[0];
  const float* W    = (const float*)d_in[1];
  const float* bvec = (const float*)d_in[2];
  const float* cvec = (const float*)d_in[3];
  const float* fc1w = (const float*)d_in[4];
  const float* fc1b = (const float*)d_in[5];
  const float* fc2w = (const float*)d_in[6];
  const float* fc2b = (const float*)d_in[7];

  if (ws_size < WS_FLOATS * sizeof(float)) return;

  float* ws      = (float*)d_ws;
  float* temps   = ws + OFF_TEMPS;
  unsigned* keys = (unsigned*)(ws + OFF_KEYS);
  float4* Wp     = (float4*)(ws + OFF_WP);
  float4* Wtp    = (float4*)(ws + OFF_WTP);
  float* fc2wT   = ws + OFF_F2T;
  float* x1      = ws + OFF_X1;
  float* bmod    = ws + OFF_BMOD;
  float* cmod    = ws + OFF_CMOD;
  float* out     = (float*)d_out;

  hipLaunchKernelGGL(kInitMeta, dim3(1), dim3(64), 0, stream, temps, keys);
  hipLaunchKernelGGL(kWp, dim3(256), dim3(256), 0, stream, W, Wp);
  hipLaunchKernelGGL(kWtp, dim3(256), dim3(256), 0, stream, W, Wtp);
  hipLaunchKernelGGL(kTf2, dim3(256), dim3(256), 0, stream, fc2w, fc2wT);
  hipLaunchKernelGGL(kX1, dim3(2048), dim3(256), 0, stream, cond, fc1w, fc1b, x1);
  hipLaunchKernelGGL(kMod2, dim3(16384), dim3(256), 0, stream, x1, fc2wT, fc2b, bvec, cvec, bmod, cmod);
  hipLaunchKernelGGL(kGibbs, dim3(2048), dim3(128), 0, stream, Wp, Wtp, bmod, cmod, keys, temps, out);
}